// Round 1
// baseline (402.920 us; speedup 1.0000x reference)
//
#include <hip/hip_runtime.h>
#include <math.h>

#define NC 15
#define TOPKK 15
#define BG_F 15.0f

// Exact port of pairwise_riou for one (det, gt) pair.
// Candidate point order must match reference: 16 edge intersections
// (e1*4+e2), then 4 corners of box1, then 4 corners of box2.
// Sort must be stable ascending by angle (jnp.argsort default).
__device__ __forceinline__ float obb_iou(
    float cx1, float cy1, float w1, float h1, float a1,
    float cx2, float cy2, float w2, float h2, float a2) {
  const float dxs[4] = {0.5f, 0.5f, -0.5f, -0.5f};
  const float dys[4] = {-0.5f, 0.5f, 0.5f, -0.5f};
  float c1 = cosf(a1), s1 = sinf(a1), c2 = cosf(a2), s2 = sinf(a2);
  float ax[4], ay[4], bx[4], by[4];
#pragma unroll
  for (int k = 0; k < 4; k++) {
    float dx = dxs[k] * w1, dy = dys[k] * h1;
    ax[k] = cx1 + dx * c1 - dy * s1;
    ay[k] = cy1 + dx * s1 + dy * c1;
    dx = dxs[k] * w2; dy = dys[k] * h2;
    bx[k] = cx2 + dx * c2 - dy * s2;
    by[k] = cy2 + dx * s2 + dy * c2;
  }
  float qx[24], qy[24];
  int cnt = 0;
  // edge-edge intersections, order e1*4+e2
  for (int e1 = 0; e1 < 4; e1++) {
    float d1x = ax[(e1 + 1) & 3] - ax[e1], d1y = ay[(e1 + 1) & 3] - ay[e1];
    for (int e2 = 0; e2 < 4; e2++) {
      float d2x = bx[(e2 + 1) & 3] - bx[e2], d2y = by[(e2 + 1) & 3] - by[e2];
      float den = d1x * d2y - d1y * d2x;
      if (fabsf(den) > 1e-10f) {
        float qpx = bx[e2] - ax[e1], qpy = by[e2] - ay[e1];
        float t = (qpx * d2y - qpy * d2x) / den;
        float u = (qpx * d1y - qpy * d1x) / den;
        if (t >= 0.f && t <= 1.f && u >= 0.f && u <= 1.f) {
          qx[cnt] = ax[e1] + t * d1x;
          qy[cnt] = ay[e1] + t * d1y;
          cnt++;
        }
      }
    }
  }
  const float eps = 1e-6f;
  // corners of box1 inside box2
#pragma unroll
  for (int k = 0; k < 4; k++) {
    float rx = ax[k] - cx2, ry = ay[k] - cy2;
    float x = rx * c2 + ry * s2, y = -rx * s2 + ry * c2;
    if (fabsf(x) <= w2 * 0.5f + eps && fabsf(y) <= h2 * 0.5f + eps) {
      qx[cnt] = ax[k]; qy[cnt] = ay[k]; cnt++;
    }
  }
  // corners of box2 inside box1
#pragma unroll
  for (int k = 0; k < 4; k++) {
    float rx = bx[k] - cx1, ry = by[k] - cy1;
    float x = rx * c1 + ry * s1, y = -rx * s1 + ry * c1;
    if (fabsf(x) <= w1 * 0.5f + eps && fabsf(y) <= h1 * 0.5f + eps) {
      qx[cnt] = bx[k]; qy[cnt] = by[k]; cnt++;
    }
  }
  if (cnt == 0) return 0.f;
  float sx = 0.f, sy = 0.f;
  for (int k = 0; k < cnt; k++) { sx += qx[k]; sy += qy[k]; }
  float ccx = sx / (float)cnt, ccy = sy / (float)cnt;
  float ang[24];
  for (int k = 0; k < cnt; k++) ang[k] = atan2f(qy[k] - ccy, qx[k] - ccx);
  // stable insertion sort ascending by angle (ties keep original index order)
  for (int k = 1; k < cnt; k++) {
    float av = ang[k], xv = qx[k], yv = qy[k];
    int j = k - 1;
    while (j >= 0 && ang[j] > av) {
      ang[j + 1] = ang[j]; qx[j + 1] = qx[j]; qy[j + 1] = qy[j];
      j--;
    }
    ang[j + 1] = av; qx[j + 1] = xv; qy[j + 1] = yv;
  }
  float ssum = 0.f;
  for (int k = 0; k < cnt; k++) {
    int kn = (k + 1 == cnt) ? 0 : k + 1;
    float vax = qx[k] - ccx, vay = qy[k] - ccy;
    float vbx = qx[kn] - ccx, vby = qy[kn] - ccy;
    ssum += vax * vby - vay * vbx;
  }
  float inter = 0.5f * fabsf(ssum);
  float areaA = w1 * h1, areaB = w2 * h2;
  return inter / fmaxf(areaA + areaB - inter, 1e-8f);
}

// Per-point: decode det box (mirrors _decode with scaled preds) + softmax probs.
__global__ void k_prep(const float* __restrict__ pts,
                       const float* __restrict__ spp,
                       const float* __restrict__ preds,
                       const float* __restrict__ probs,
                       float* __restrict__ dec,
                       float* __restrict__ softp, int N) {
  int i = blockIdx.x * blockDim.x + threadIdx.x;
  if (i >= N) return;
  float st = spp[i];
  float d0 = preds[i * 5 + 0] * st, d1 = preds[i * 5 + 1] * st;
  float d2 = preds[i * 5 + 2] * st, d3 = preds[i * 5 + 3] * st;
  float angp = preds[i * 5 + 4];
  float c = cosf(angp), s = sinf(angp);
  float w = d0 + d2, h = d1 + d3;
  float otx = (d2 - d0) * 0.5f, oty = (d3 - d1) * 0.5f;
  float ox = c * otx - s * oty, oy = s * otx + c * oty;
  const float PI = 3.14159265358979323846f;
  // jnp.mod has divisor sign (non-negative result); fix fmodf accordingly
  float a = fmodf(angp + PI * 0.5f, PI);
  if (a < 0.f) a += PI;
  a -= PI * 0.5f;
  dec[i * 5 + 0] = pts[i * 2 + 0] + ox;
  dec[i * 5 + 1] = pts[i * 2 + 1] + oy;
  dec[i * 5 + 2] = w;
  dec[i * 5 + 3] = h;
  dec[i * 5 + 4] = a;
  // softmax with max subtraction (jax.nn.softmax)
  float pv[NC];
  float m = -1e30f;
#pragma unroll
  for (int k = 0; k < NC; k++) { pv[k] = probs[i * NC + k]; m = fmaxf(m, pv[k]); }
  float ss = 0.f;
#pragma unroll
  for (int k = 0; k < NC; k++) { pv[k] = expf(pv[k] - m); ss += pv[k]; }
#pragma unroll
  for (int k = 0; k < NC; k++) softp[i * NC + k] = pv[k] / ss;
}

// Per (point, gt) pair: bbox_targets, centerness, valid; IoU only when valid.
__global__ void k_pair(const float* __restrict__ pts,
                       const float* __restrict__ rr,
                       const float* __restrict__ spp,
                       const float* __restrict__ gtb,
                       const int* __restrict__ gtl,
                       const float* __restrict__ dec,
                       const float* __restrict__ softp,
                       float* __restrict__ cost,
                       float* __restrict__ cent,
                       unsigned char* __restrict__ mask,
                       int N, int G) {
  int t = blockIdx.x * blockDim.x + threadIdx.x;
  if (t >= N * G) return;
  int g = t % G, i = t / G;
  float gx = gtb[g * 5 + 0], gy = gtb[g * 5 + 1];
  float gw = gtb[g * 5 + 2], gh = gtb[g * 5 + 3], ga = gtb[g * 5 + 4];
  float cg = cosf(ga), sg = sinf(ga);
  float px = pts[i * 2 + 0] - gx, py = pts[i * 2 + 1] - gy;
  float ox = px * cg + py * sg;
  float oy = -px * sg + py * cg;
  float hw = gw * 0.5f, hh = gh * 0.5f;
  float l = hw + ox, tt = hh + oy, r = hw - ox, b = hh - oy;
  float minb = fminf(fminf(l, tt), fminf(r, b));
  float maxb = fmaxf(fmaxf(l, tt), fmaxf(r, b));
  float nx = 2.f * ox / gw, ny = 2.f * oy / gh;
  float ctn = fmaxf(1.f - sqrtf((nx * nx + ny * ny + 1e-8f) * 0.5f), 0.f);
  bool inside_gt = minb > 0.f;
  bool inside_rr = (maxb >= rr[i * 2 + 0]) && (maxb <= rr[i * 2 + 1]);
  float cr = 1.5f * spp[i];
  inside_gt = inside_gt && (fabsf(ox) < cr) && (fabsf(oy) < cr);
  float cval = 0.f;
  if (inside_gt && inside_rr) {
    float iou = obb_iou(dec[i * 5 + 0], dec[i * 5 + 1], dec[i * 5 + 2],
                        dec[i * 5 + 3], dec[i * 5 + 4],
                        gx, gy, gw, gh, ga);
    cval = 0.2f * ctn + 0.2f * iou + 0.6f * softp[i * NC + gtl[g]];
  }
  cost[i * G + g] = cval;
  cent[i * G + g] = ctn;
  mask[i * G + g] = 0;
}

// One block per gt: anchor (argmax centerness, first occurrence) + iterative
// top-15 of the cost column (value desc, index asc = lax.top_k tie rule).
__global__ void k_topk(const float* __restrict__ cent,
                       float* __restrict__ cost,
                       unsigned char* __restrict__ mask,
                       int* __restrict__ anchor,
                       int* __restrict__ counts,
                       int N, int G) {
  int g = blockIdx.x;
  int tid = threadIdx.x;
  __shared__ float sv[256];
  __shared__ int si[256];
  __shared__ int stop;
  // anchor = argmax over points of centerness[:, g]
  float bv = -1e30f; int bi = 0x7fffffff;
  for (int i = tid; i < N; i += 256) {
    float v = cent[i * G + g];
    if (v > bv) { bv = v; bi = i; }  // ascending i => first occurrence kept
  }
  sv[tid] = bv; si[tid] = bi;
  __syncthreads();
  for (int o = 128; o > 0; o >>= 1) {
    if (tid < o) {
      if (sv[tid + o] > sv[tid] ||
          (sv[tid + o] == sv[tid] && si[tid + o] < si[tid])) {
        sv[tid] = sv[tid + o]; si[tid] = si[tid + o];
      }
    }
    __syncthreads();
  }
  if (tid == 0) { anchor[g] = si[0]; counts[g] = 0; }
  // top-15, destructive marking
  for (int rnd = 0; rnd < TOPKK; rnd++) {
    __syncthreads();
    bv = -1e30f; bi = 0x7fffffff;
    for (int i = tid; i < N; i += 256) {
      float v = cost[i * G + g];
      if (v > bv) { bv = v; bi = i; }
    }
    sv[tid] = bv; si[tid] = bi;
    __syncthreads();
    for (int o = 128; o > 0; o >>= 1) {
      if (tid < o) {
        if (sv[tid + o] > sv[tid] ||
            (sv[tid + o] == sv[tid] && si[tid + o] < si[tid])) {
          sv[tid] = sv[tid + o]; si[tid] = si[tid + o];
        }
      }
      __syncthreads();
    }
    if (tid == 0) {
      if (sv[0] > 0.f) {
        mask[si[0] * G + g] = 1;
        cost[si[0] * G + g] = -1e30f;
        stop = 0;
      } else {
        stop = 1;  // remaining vals are 0 -> never masked (vals != 0 filter)
      }
    }
    __syncthreads();
    if (stop) break;
  }
}

// Per point: areas = w*h * topk_mask; argmax (first occurrence), labels, counts.
__global__ void k_assign(const unsigned char* __restrict__ mask,
                         const float* __restrict__ gtb,
                         const int* __restrict__ gtl,
                         int* __restrict__ inds,
                         int* __restrict__ counts,
                         float* __restrict__ out_labels,
                         int N, int G) {
  int i = blockIdx.x * blockDim.x + threadIdx.x;
  if (i >= N) return;
  float ma = 0.f; int ind = 0;
  for (int g = 0; g < G; g++) {
    if (mask[i * G + g]) {
      float a = gtb[g * 5 + 2] * gtb[g * 5 + 3];
      if (a > ma) { ma = a; ind = g; }
    }
  }
  inds[i] = ind;
  out_labels[i] = (ma == 0.f) ? BG_F : (float)gtl[ind];
  if (ma != 0.f) atomicAdd(&counts[ind], 1);
}

// Serial: unmatched gts claim their anchor point (ascending g, last wins).
__global__ void k_fix(const int* __restrict__ counts,
                      const int* __restrict__ anchor,
                      const int* __restrict__ gtl,
                      int* __restrict__ inds,
                      float* __restrict__ out_labels,
                      int G) {
  if (blockIdx.x == 0 && threadIdx.x == 0) {
    for (int g = 0; g < G; g++) {
      if (counts[g] == 0) {
        int a = anchor[g];
        inds[a] = g;
        out_labels[a] = (float)gtl[g];
      }
    }
  }
}

// Per point: recompute bbox_targets at final inds, /stride; angle target.
__global__ void k_final(const float* __restrict__ pts,
                        const float* __restrict__ spp,
                        const float* __restrict__ gtb,
                        const int* __restrict__ inds,
                        float* __restrict__ out_bt,
                        float* __restrict__ out_at,
                        int N) {
  int i = blockIdx.x * blockDim.x + threadIdx.x;
  if (i >= N) return;
  int g = inds[i];
  float gx = gtb[g * 5 + 0], gy = gtb[g * 5 + 1];
  float gw = gtb[g * 5 + 2], gh = gtb[g * 5 + 3], ga = gtb[g * 5 + 4];
  float cg = cosf(ga), sg = sinf(ga);
  float px = pts[i * 2 + 0] - gx, py = pts[i * 2 + 1] - gy;
  float ox = px * cg + py * sg, oy = -px * sg + py * cg;
  float st = spp[i];
  out_bt[i * 4 + 0] = (gw * 0.5f + ox) / st;
  out_bt[i * 4 + 1] = (gh * 0.5f + oy) / st;
  out_bt[i * 4 + 2] = (gw * 0.5f - ox) / st;
  out_bt[i * 4 + 3] = (gh * 0.5f - oy) / st;
  out_at[i] = ga;
}

extern "C" void kernel_launch(void* const* d_in, const int* in_sizes, int n_in,
                              void* d_out, int out_size, void* d_ws, size_t ws_size,
                              hipStream_t stream) {
  const float* pts   = (const float*)d_in[0];
  const float* rr    = (const float*)d_in[1];
  const float* spp   = (const float*)d_in[2];
  const float* gtb   = (const float*)d_in[3];
  const int*   gtl   = (const int*)d_in[4];
  const float* preds = (const float*)d_in[5];
  const float* probs = (const float*)d_in[6];
  int N = in_sizes[0] / 2;
  int G = in_sizes[3] / 5;

  float* out = (float*)d_out;
  float* out_labels = out;            // N
  float* out_bt     = out + N;        // N*4
  float* out_at     = out + 5 * (size_t)N;  // N

  float* cost  = (float*)d_ws;
  float* cent  = cost + (size_t)N * G;
  float* dec   = cent + (size_t)N * G;
  float* softp = dec + (size_t)N * 5;
  int* inds    = (int*)(softp + (size_t)N * NC);
  int* counts  = inds + N;
  int* anchor  = counts + G;
  unsigned char* mask = (unsigned char*)(anchor + G);

  const int thr = 256;
  hipLaunchKernelGGL(k_prep, dim3((N + thr - 1) / thr), dim3(thr), 0, stream,
                     pts, spp, preds, probs, dec, softp, N);
  int T = N * G;
  hipLaunchKernelGGL(k_pair, dim3((T + thr - 1) / thr), dim3(thr), 0, stream,
                     pts, rr, spp, gtb, gtl, dec, softp, cost, cent, mask, N, G);
  hipLaunchKernelGGL(k_topk, dim3(G), dim3(256), 0, stream,
                     cent, cost, mask, anchor, counts, N, G);
  hipLaunchKernelGGL(k_assign, dim3((N + thr - 1) / thr), dim3(thr), 0, stream,
                     mask, gtb, gtl, inds, counts, out_labels, N, G);
  hipLaunchKernelGGL(k_fix, dim3(1), dim3(64), 0, stream,
                     counts, anchor, gtl, inds, out_labels, G);
  hipLaunchKernelGGL(k_final, dim3((N + thr - 1) / thr), dim3(thr), 0, stream,
                     pts, spp, gtb, inds, out_bt, out_at, N);
}

// Round 2
// 167.680 us; speedup vs baseline: 2.4029x; 2.4029x over previous
//
#include <hip/hip_runtime.h>
#include <math.h>

#define NC 15
#define TOPKK 15
#define BG_F 15.0f
#define MAXC 256

// Exact port of pairwise_riou for one (det, gt) pair.
// Candidate point order matches reference: 16 edge intersections (e1*4+e2),
// then 4 corners of box1, then 4 corners of box2. Stable ascending sort by
// angle replicates jnp.argsort.
__device__ __forceinline__ float obb_iou(
    float cx1, float cy1, float w1, float h1, float a1,
    float cx2, float cy2, float w2, float h2, float a2) {
  const float dxs[4] = {0.5f, 0.5f, -0.5f, -0.5f};
  const float dys[4] = {-0.5f, 0.5f, 0.5f, -0.5f};
  float c1 = cosf(a1), s1 = sinf(a1), c2 = cosf(a2), s2 = sinf(a2);
  float ax[4], ay[4], bx[4], by[4];
#pragma unroll
  for (int k = 0; k < 4; k++) {
    float dx = dxs[k] * w1, dy = dys[k] * h1;
    ax[k] = cx1 + dx * c1 - dy * s1;
    ay[k] = cy1 + dx * s1 + dy * c1;
    dx = dxs[k] * w2; dy = dys[k] * h2;
    bx[k] = cx2 + dx * c2 - dy * s2;
    by[k] = cy2 + dx * s2 + dy * c2;
  }
  float qx[24], qy[24];
  int cnt = 0;
  for (int e1 = 0; e1 < 4; e1++) {
    float d1x = ax[(e1 + 1) & 3] - ax[e1], d1y = ay[(e1 + 1) & 3] - ay[e1];
    for (int e2 = 0; e2 < 4; e2++) {
      float d2x = bx[(e2 + 1) & 3] - bx[e2], d2y = by[(e2 + 1) & 3] - by[e2];
      float den = d1x * d2y - d1y * d2x;
      if (fabsf(den) > 1e-10f) {
        float qpx = bx[e2] - ax[e1], qpy = by[e2] - ay[e1];
        float t = (qpx * d2y - qpy * d2x) / den;
        float u = (qpx * d1y - qpy * d1x) / den;
        if (t >= 0.f && t <= 1.f && u >= 0.f && u <= 1.f) {
          qx[cnt] = ax[e1] + t * d1x;
          qy[cnt] = ay[e1] + t * d1y;
          cnt++;
        }
      }
    }
  }
  const float eps = 1e-6f;
#pragma unroll
  for (int k = 0; k < 4; k++) {
    float rx = ax[k] - cx2, ry = ay[k] - cy2;
    float x = rx * c2 + ry * s2, y = -rx * s2 + ry * c2;
    if (fabsf(x) <= w2 * 0.5f + eps && fabsf(y) <= h2 * 0.5f + eps) {
      qx[cnt] = ax[k]; qy[cnt] = ay[k]; cnt++;
    }
  }
#pragma unroll
  for (int k = 0; k < 4; k++) {
    float rx = bx[k] - cx1, ry = by[k] - cy1;
    float x = rx * c1 + ry * s1, y = -rx * s1 + ry * c1;
    if (fabsf(x) <= w1 * 0.5f + eps && fabsf(y) <= h1 * 0.5f + eps) {
      qx[cnt] = bx[k]; qy[cnt] = by[k]; cnt++;
    }
  }
  if (cnt == 0) return 0.f;
  float sx = 0.f, sy = 0.f;
  for (int k = 0; k < cnt; k++) { sx += qx[k]; sy += qy[k]; }
  float ccx = sx / (float)cnt, ccy = sy / (float)cnt;
  float ang[24];
  for (int k = 0; k < cnt; k++) ang[k] = atan2f(qy[k] - ccy, qx[k] - ccx);
  for (int k = 1; k < cnt; k++) {
    float av = ang[k], xv = qx[k], yv = qy[k];
    int j = k - 1;
    while (j >= 0 && ang[j] > av) {
      ang[j + 1] = ang[j]; qx[j + 1] = qx[j]; qy[j + 1] = qy[j];
      j--;
    }
    ang[j + 1] = av; qx[j + 1] = xv; qy[j + 1] = yv;
  }
  float ssum = 0.f;
  for (int k = 0; k < cnt; k++) {
    int kn = (k + 1 == cnt) ? 0 : k + 1;
    float vax = qx[k] - ccx, vay = qy[k] - ccy;
    float vbx = qx[kn] - ccx, vby = qy[kn] - ccy;
    ssum += vax * vby - vay * vbx;
  }
  float inter = 0.5f * fabsf(ssum);
  float areaA = w1 * h1, areaB = w2 * h2;
  return inter / fmaxf(areaA + areaB - inter, 1e-8f);
}

// Per-gt centerness argmax over all points (replaces dense cent matrix).
// key = (ctn_bits << 32) | (~i)  -> atomicMax keeps max ctn, min i on ties.
__global__ void k_cent(const float* __restrict__ pts,
                       const float* __restrict__ gtb,
                       unsigned long long* __restrict__ cent_key,
                       int N, int G) {
  int g = blockIdx.y;
  int i = blockIdx.x * blockDim.x + threadIdx.x;
  unsigned long long key = 0ull;
  if (i < N) {
    float gx = gtb[g * 5 + 0], gy = gtb[g * 5 + 1];
    float gw = gtb[g * 5 + 2], gh = gtb[g * 5 + 3], ga = gtb[g * 5 + 4];
    float cg = cosf(ga), sg = sinf(ga);
    float px = pts[i * 2 + 0] - gx, py = pts[i * 2 + 1] - gy;
    float ox = px * cg + py * sg, oy = -px * sg + py * cg;
    float nx = 2.f * ox / gw, ny = 2.f * oy / gh;
    float ctn = fmaxf(1.f - sqrtf((nx * nx + ny * ny + 1e-8f) * 0.5f), 0.f);
    key = ((unsigned long long)__float_as_uint(ctn) << 32) |
          (unsigned long long)(0xFFFFFFFFu - (unsigned)i);
  }
  __shared__ unsigned long long sk[256];
  sk[threadIdx.x] = key;
  __syncthreads();
  for (int o = 128; o > 0; o >>= 1) {
    if (threadIdx.x < o) {
      unsigned long long other = sk[threadIdx.x + o];
      if (other > sk[threadIdx.x]) sk[threadIdx.x] = other;
    }
    __syncthreads();
  }
  if (threadIdx.x == 0) atomicMax(&cent_key[g], sk[0]);
}

// Per (point, gt): validity test; only valid pairs do the heavy work
// (softmax + decode + rotated IoU) and append to the per-gt candidate list.
__global__ void k_pair(const float* __restrict__ pts,
                       const float* __restrict__ rr,
                       const float* __restrict__ spp,
                       const float* __restrict__ gtb,
                       const int* __restrict__ gtl,
                       const float* __restrict__ preds,
                       const float* __restrict__ probs,
                       int* __restrict__ cand_cnt,
                       int* __restrict__ cand_i,
                       float* __restrict__ cand_v,
                       int N, int G) {
  int t = blockIdx.x * blockDim.x + threadIdx.x;
  if (t >= N * G) return;
  int g = t % G, i = t / G;
  float gx = gtb[g * 5 + 0], gy = gtb[g * 5 + 1];
  float gw = gtb[g * 5 + 2], gh = gtb[g * 5 + 3], ga = gtb[g * 5 + 4];
  float cg = cosf(ga), sg = sinf(ga);
  float px = pts[i * 2 + 0] - gx, py = pts[i * 2 + 1] - gy;
  float ox = px * cg + py * sg;
  float oy = -px * sg + py * cg;
  float hw = gw * 0.5f, hh = gh * 0.5f;
  float l = hw + ox, tt = hh + oy, r = hw - ox, b = hh - oy;
  float minb = fminf(fminf(l, tt), fminf(r, b));
  float maxb = fmaxf(fmaxf(l, tt), fmaxf(r, b));
  bool inside_gt = minb > 0.f;
  bool inside_rr = (maxb >= rr[i * 2 + 0]) && (maxb <= rr[i * 2 + 1]);
  float st = spp[i];
  float cr = 1.5f * st;
  inside_gt = inside_gt && (fabsf(ox) < cr) && (fabsf(oy) < cr);
  if (!(inside_gt && inside_rr)) return;

  float nx = 2.f * ox / gw, ny = 2.f * oy / gh;
  float ctn = fmaxf(1.f - sqrtf((nx * nx + ny * ny + 1e-8f) * 0.5f), 0.f);

  // softmax prob of this gt's label (jax.nn.softmax with max subtraction)
  float pv[NC];
  float m = -1e30f;
#pragma unroll
  for (int k = 0; k < NC; k++) { pv[k] = probs[i * NC + k]; m = fmaxf(m, pv[k]); }
  float ss = 0.f;
#pragma unroll
  for (int k = 0; k < NC; k++) { pv[k] = expf(pv[k] - m); ss += pv[k]; }
  float prob = pv[gtl[g]] / ss;

  // decode det box (mirrors _decode with stride-scaled preds)
  float d0 = preds[i * 5 + 0] * st, d1 = preds[i * 5 + 1] * st;
  float d2 = preds[i * 5 + 2] * st, d3 = preds[i * 5 + 3] * st;
  float angp = preds[i * 5 + 4];
  float c = cosf(angp), s = sinf(angp);
  float w = d0 + d2, h = d1 + d3;
  float otx = (d2 - d0) * 0.5f, oty = (d3 - d1) * 0.5f;
  float dox = c * otx - s * oty, doy = s * otx + c * oty;
  const float PI = 3.14159265358979323846f;
  float a = fmodf(angp + PI * 0.5f, PI);
  if (a < 0.f) a += PI;
  a -= PI * 0.5f;
  float dcx = pts[i * 2 + 0] + dox, dcy = pts[i * 2 + 1] + doy;

  float iou = obb_iou(dcx, dcy, w, h, a, gx, gy, gw, gh, ga);
  float cval = 0.2f * ctn + 0.2f * iou + 0.6f * prob;

  int slot = atomicAdd(&cand_cnt[g], 1);
  if (slot < MAXC) {
    cand_i[g * MAXC + slot] = i;
    cand_v[g * MAXC + slot] = cval;
  }
}

// Per gt: serial top-15 over the (small) candidate list, exact lax.top_k
// tie rule (value desc, index asc). Winners atomicMax the per-point area key:
// key = (area_bits << 32) | (G-1-g)  -> max area, min g on ties.
__global__ void k_top(const int* __restrict__ cand_cnt,
                      int* __restrict__ cand_i,
                      float* __restrict__ cand_v,
                      const float* __restrict__ gtb,
                      unsigned long long* __restrict__ point_key,
                      int G) {
  int g = blockIdx.x;
  if (threadIdx.x != 0) return;
  int cnt = cand_cnt[g];
  if (cnt > MAXC) cnt = MAXC;
  float area = gtb[g * 5 + 2] * gtb[g * 5 + 3];
  unsigned long long hi = ((unsigned long long)__float_as_uint(area)) << 32;
  unsigned long long lo = (unsigned long long)(unsigned)(G - 1 - g);
  for (int r = 0; r < TOPKK && r < cnt; r++) {
    float bv = 0.f; int bj = -1, bi = 0x7fffffff;
    for (int j = 0; j < cnt; j++) {
      float v = cand_v[g * MAXC + j];
      if (v <= 0.f) continue;  // consumed or nonpositive (vals != 0 filter)
      int ii = cand_i[g * MAXC + j];
      if (v > bv || (v == bv && ii < bi)) { bv = v; bi = ii; bj = j; }
    }
    if (bj < 0) break;
    cand_v[g * MAXC + bj] = -1.f;
    atomicMax(&point_key[bi], hi | lo);
  }
}

// Per point: resolve key -> (ind, label), count matches, write bt/at.
__global__ void k_assign(const unsigned long long* __restrict__ point_key,
                         const float* __restrict__ pts,
                         const float* __restrict__ spp,
                         const float* __restrict__ gtb,
                         const int* __restrict__ gtl,
                         int* __restrict__ counts,
                         float* __restrict__ out_labels,
                         float* __restrict__ out_bt,
                         float* __restrict__ out_at,
                         int N, int G) {
  int i = blockIdx.x * blockDim.x + threadIdx.x;
  if (i >= N) return;
  unsigned long long key = point_key[i];
  int g = 0;
  if (key != 0ull) {
    g = (G - 1) - (int)(key & 0xFFFFFFFFull);
    out_labels[i] = (float)gtl[g];
    atomicAdd(&counts[g], 1);
  } else {
    out_labels[i] = BG_F;  // argmax of all-zero row -> ind 0, label BG
  }
  float gx = gtb[g * 5 + 0], gy = gtb[g * 5 + 1];
  float gw = gtb[g * 5 + 2], gh = gtb[g * 5 + 3], ga = gtb[g * 5 + 4];
  float cg = cosf(ga), sg = sinf(ga);
  float px = pts[i * 2 + 0] - gx, py = pts[i * 2 + 1] - gy;
  float ox = px * cg + py * sg, oy = -px * sg + py * cg;
  float st = spp[i];
  out_bt[i * 4 + 0] = (gw * 0.5f + ox) / st;
  out_bt[i * 4 + 1] = (gh * 0.5f + oy) / st;
  out_bt[i * 4 + 2] = (gw * 0.5f - ox) / st;
  out_bt[i * 4 + 3] = (gh * 0.5f - oy) / st;
  out_at[i] = ga;
}

// Serial: unmatched gts claim their anchor point (ascending g, overwrite =
// last wins, matching XLA scatter), rewriting that point's outputs.
__global__ void k_fix(const int* __restrict__ counts,
                      const unsigned long long* __restrict__ cent_key,
                      const float* __restrict__ pts,
                      const float* __restrict__ spp,
                      const float* __restrict__ gtb,
                      const int* __restrict__ gtl,
                      float* __restrict__ out_labels,
                      float* __restrict__ out_bt,
                      float* __restrict__ out_at,
                      int G) {
  if (blockIdx.x != 0 || threadIdx.x != 0) return;
  for (int g = 0; g < G; g++) {
    if (counts[g] == 0) {
      unsigned i = 0xFFFFFFFFu - (unsigned)(cent_key[g] & 0xFFFFFFFFull);
      out_labels[i] = (float)gtl[g];
      float gx = gtb[g * 5 + 0], gy = gtb[g * 5 + 1];
      float gw = gtb[g * 5 + 2], gh = gtb[g * 5 + 3], ga = gtb[g * 5 + 4];
      float cg = cosf(ga), sg = sinf(ga);
      float px = pts[i * 2 + 0] - gx, py = pts[i * 2 + 1] - gy;
      float ox = px * cg + py * sg, oy = -px * sg + py * cg;
      float st = spp[i];
      out_bt[i * 4 + 0] = (gw * 0.5f + ox) / st;
      out_bt[i * 4 + 1] = (gh * 0.5f + oy) / st;
      out_bt[i * 4 + 2] = (gw * 0.5f - ox) / st;
      out_bt[i * 4 + 3] = (gh * 0.5f - oy) / st;
      out_at[i] = ga;
    }
  }
}

extern "C" void kernel_launch(void* const* d_in, const int* in_sizes, int n_in,
                              void* d_out, int out_size, void* d_ws, size_t ws_size,
                              hipStream_t stream) {
  const float* pts   = (const float*)d_in[0];
  const float* rr    = (const float*)d_in[1];
  const float* spp   = (const float*)d_in[2];
  const float* gtb   = (const float*)d_in[3];
  const int*   gtl   = (const int*)d_in[4];
  const float* preds = (const float*)d_in[5];
  const float* probs = (const float*)d_in[6];
  int N = in_sizes[0] / 2;
  int G = in_sizes[3] / 5;

  float* out = (float*)d_out;
  float* out_labels = out;                   // N
  float* out_bt     = out + N;               // N*4
  float* out_at     = out + 5 * (size_t)N;   // N

  // workspace layout (8-byte aligned first)
  unsigned long long* point_key = (unsigned long long*)d_ws;   // N
  unsigned long long* cent_key  = point_key + N;               // G
  int* cand_cnt = (int*)(cent_key + G);                        // G
  int* counts   = cand_cnt + G;                                // G
  int* cand_i   = counts + G;                                  // G*MAXC
  float* cand_v = (float*)(cand_i + (size_t)G * MAXC);         // G*MAXC

  size_t zbytes = (size_t)N * 8 + (size_t)G * 8 + (size_t)G * 4 * 2;
  hipMemsetAsync(d_ws, 0, zbytes, stream);

  const int thr = 256;
  dim3 cg((N + thr - 1) / thr, G);
  hipLaunchKernelGGL(k_cent, cg, dim3(thr), 0, stream, pts, gtb, cent_key, N, G);
  int T = N * G;
  hipLaunchKernelGGL(k_pair, dim3((T + thr - 1) / thr), dim3(thr), 0, stream,
                     pts, rr, spp, gtb, gtl, preds, probs,
                     cand_cnt, cand_i, cand_v, N, G);
  hipLaunchKernelGGL(k_top, dim3(G), dim3(64), 0, stream,
                     cand_cnt, cand_i, cand_v, gtb, point_key, G);
  hipLaunchKernelGGL(k_assign, dim3((N + thr - 1) / thr), dim3(thr), 0, stream,
                     point_key, pts, spp, gtb, gtl, counts,
                     out_labels, out_bt, out_at, N, G);
  hipLaunchKernelGGL(k_fix, dim3(1), dim3(64), 0, stream,
                     counts, cent_key, pts, spp, gtb, gtl,
                     out_labels, out_bt, out_at, G);
}

// Round 3
// 133.233 us; speedup vs baseline: 3.0242x; 1.2586x over previous
//
#include <hip/hip_runtime.h>
#include <math.h>

#define NC 15
#define TOPKK 15
#define BG_F 15.0f
#define MAXC 256

// Exact port of pairwise_riou for one (det, gt) pair.
// Candidate point order matches reference: 16 edge intersections (e1*4+e2),
// then 4 corners of box1, then 4 corners of box2. Stable ascending sort by
// angle replicates jnp.argsort.
__device__ __forceinline__ float obb_iou(
    float cx1, float cy1, float w1, float h1, float a1,
    float cx2, float cy2, float w2, float h2, float a2) {
  const float dxs[4] = {0.5f, 0.5f, -0.5f, -0.5f};
  const float dys[4] = {-0.5f, 0.5f, 0.5f, -0.5f};
  float c1 = cosf(a1), s1 = sinf(a1), c2 = cosf(a2), s2 = sinf(a2);
  float ax[4], ay[4], bx[4], by[4];
#pragma unroll
  for (int k = 0; k < 4; k++) {
    float dx = dxs[k] * w1, dy = dys[k] * h1;
    ax[k] = cx1 + dx * c1 - dy * s1;
    ay[k] = cy1 + dx * s1 + dy * c1;
    dx = dxs[k] * w2; dy = dys[k] * h2;
    bx[k] = cx2 + dx * c2 - dy * s2;
    by[k] = cy2 + dx * s2 + dy * c2;
  }
  float qx[24], qy[24];
  int cnt = 0;
  for (int e1 = 0; e1 < 4; e1++) {
    float d1x = ax[(e1 + 1) & 3] - ax[e1], d1y = ay[(e1 + 1) & 3] - ay[e1];
    for (int e2 = 0; e2 < 4; e2++) {
      float d2x = bx[(e2 + 1) & 3] - bx[e2], d2y = by[(e2 + 1) & 3] - by[e2];
      float den = d1x * d2y - d1y * d2x;
      if (fabsf(den) > 1e-10f) {
        float qpx = bx[e2] - ax[e1], qpy = by[e2] - ay[e1];
        float t = (qpx * d2y - qpy * d2x) / den;
        float u = (qpx * d1y - qpy * d1x) / den;
        if (t >= 0.f && t <= 1.f && u >= 0.f && u <= 1.f) {
          qx[cnt] = ax[e1] + t * d1x;
          qy[cnt] = ay[e1] + t * d1y;
          cnt++;
        }
      }
    }
  }
  const float eps = 1e-6f;
#pragma unroll
  for (int k = 0; k < 4; k++) {
    float rx = ax[k] - cx2, ry = ay[k] - cy2;
    float x = rx * c2 + ry * s2, y = -rx * s2 + ry * c2;
    if (fabsf(x) <= w2 * 0.5f + eps && fabsf(y) <= h2 * 0.5f + eps) {
      qx[cnt] = ax[k]; qy[cnt] = ay[k]; cnt++;
    }
  }
#pragma unroll
  for (int k = 0; k < 4; k++) {
    float rx = bx[k] - cx1, ry = by[k] - cy1;
    float x = rx * c1 + ry * s1, y = -rx * s1 + ry * c1;
    if (fabsf(x) <= w1 * 0.5f + eps && fabsf(y) <= h1 * 0.5f + eps) {
      qx[cnt] = bx[k]; qy[cnt] = by[k]; cnt++;
    }
  }
  if (cnt == 0) return 0.f;
  float sx = 0.f, sy = 0.f;
  for (int k = 0; k < cnt; k++) { sx += qx[k]; sy += qy[k]; }
  float ccx = sx / (float)cnt, ccy = sy / (float)cnt;
  float ang[24];
  for (int k = 0; k < cnt; k++) ang[k] = atan2f(qy[k] - ccy, qx[k] - ccx);
  for (int k = 1; k < cnt; k++) {
    float av = ang[k], xv = qx[k], yv = qy[k];
    int j = k - 1;
    while (j >= 0 && ang[j] > av) {
      ang[j + 1] = ang[j]; qx[j + 1] = qx[j]; qy[j + 1] = qy[j];
      j--;
    }
    ang[j + 1] = av; qx[j + 1] = xv; qy[j + 1] = yv;
  }
  float ssum = 0.f;
  for (int k = 0; k < cnt; k++) {
    int kn = (k + 1 == cnt) ? 0 : k + 1;
    float vax = qx[k] - ccx, vay = qy[k] - ccy;
    float vbx = qx[kn] - ccx, vby = qy[kn] - ccy;
    ssum += vax * vby - vay * vbx;
  }
  float inter = 0.5f * fabsf(ssum);
  float areaA = w1 * h1, areaB = w2 * h2;
  return inter / fmaxf(areaA + areaB - inter, 1e-8f);
}

// Fused: per-gt centerness argmax (block reduce + 1 atomicMax per block) +
// validity scan with wave-aggregated candidate append.
// Layout: blockIdx.x = g * BPG + i_chunk -> gtb loads are wave-uniform,
// pts/rr/spp coalesced.
__global__ void k_scanc(const float* __restrict__ pts,
                        const float* __restrict__ rr,
                        const float* __restrict__ spp,
                        const float* __restrict__ gtb,
                        unsigned long long* __restrict__ cent_key,
                        int* __restrict__ cand_cnt,
                        int* __restrict__ cand_i,
                        int N, int G, int BPG) {
  int g = blockIdx.x / BPG;
  int i = (blockIdx.x % BPG) * blockDim.x + threadIdx.x;
  float gx = gtb[g * 5 + 0], gy = gtb[g * 5 + 1];
  float gw = gtb[g * 5 + 2], gh = gtb[g * 5 + 3], ga = gtb[g * 5 + 4];
  float cg = cosf(ga), sg = sinf(ga);
  unsigned long long key = 0ull;
  bool valid = false;
  if (i < N) {
    float px = pts[i * 2 + 0] - gx, py = pts[i * 2 + 1] - gy;
    float ox = px * cg + py * sg, oy = -px * sg + py * cg;
    float nx = 2.f * ox / gw, ny = 2.f * oy / gh;
    float ctn = fmaxf(1.f - sqrtf((nx * nx + ny * ny + 1e-8f) * 0.5f), 0.f);
    key = ((unsigned long long)__float_as_uint(ctn) << 32) |
          (unsigned long long)(0xFFFFFFFFu - (unsigned)i);
    float hw = gw * 0.5f, hh = gh * 0.5f;
    float l = hw + ox, tt = hh + oy, r = hw - ox, b = hh - oy;
    float minb = fminf(fminf(l, tt), fminf(r, b));
    float maxb = fmaxf(fmaxf(l, tt), fmaxf(r, b));
    float cr = 1.5f * spp[i];
    valid = (minb > 0.f) && (fabsf(ox) < cr) && (fabsf(oy) < cr) &&
            (maxb >= rr[i * 2 + 0]) && (maxb <= rr[i * 2 + 1]);
  }
  __shared__ unsigned long long sk[256];
  sk[threadIdx.x] = key;
  __syncthreads();
  for (int o = 128; o > 0; o >>= 1) {
    if (threadIdx.x < o) {
      unsigned long long other = sk[threadIdx.x + o];
      if (other > sk[threadIdx.x]) sk[threadIdx.x] = other;
    }
    __syncthreads();
  }
  if (threadIdx.x == 0) atomicMax(&cent_key[g], sk[0]);
  // wave-aggregated append of valid point indices
  unsigned long long ball = __ballot(valid);
  if (ball) {
    int lane = threadIdx.x & 63;
    int leader = __ffsll((unsigned long long)ball) - 1;
    int base = 0;
    if (lane == leader) base = atomicAdd(&cand_cnt[g], __popcll(ball));
    base = __shfl(base, leader, 64);
    if (valid) {
      int off = __popcll(ball & ((1ull << lane) - 1ull));
      int slot = base + off;
      if (slot < MAXC) cand_i[g * MAXC + slot] = i;
    }
  }
}

// Dense heavy phase: block = gt, tid = candidate slot. All lanes active ->
// the scratch-array polygon clip runs at full wave utilization.
__global__ void k_iou(const float* __restrict__ pts,
                      const float* __restrict__ spp,
                      const float* __restrict__ gtb,
                      const int* __restrict__ gtl,
                      const float* __restrict__ preds,
                      const float* __restrict__ probs,
                      const int* __restrict__ cand_cnt,
                      const int* __restrict__ cand_i,
                      float* __restrict__ cand_v,
                      int G) {
  int g = blockIdx.x;
  int j = threadIdx.x;
  int cnt = cand_cnt[g];
  if (cnt > MAXC) cnt = MAXC;
  if (j >= cnt) return;
  int i = cand_i[g * MAXC + j];
  float gx = gtb[g * 5 + 0], gy = gtb[g * 5 + 1];
  float gw = gtb[g * 5 + 2], gh = gtb[g * 5 + 3], ga = gtb[g * 5 + 4];
  float cg = cosf(ga), sg = sinf(ga);
  float ptx = pts[i * 2 + 0], pty = pts[i * 2 + 1];
  float px = ptx - gx, py = pty - gy;
  float ox = px * cg + py * sg, oy = -px * sg + py * cg;
  float nx = 2.f * ox / gw, ny = 2.f * oy / gh;
  float ctn = fmaxf(1.f - sqrtf((nx * nx + ny * ny + 1e-8f) * 0.5f), 0.f);

  // softmax prob of this gt's label
  float pv[NC];
  float m = -1e30f;
#pragma unroll
  for (int k = 0; k < NC; k++) { pv[k] = probs[i * NC + k]; m = fmaxf(m, pv[k]); }
  float ss = 0.f;
#pragma unroll
  for (int k = 0; k < NC; k++) { pv[k] = expf(pv[k] - m); ss += pv[k]; }
  float prob = pv[gtl[g]] / ss;

  // decode det box (mirrors _decode with stride-scaled preds)
  float st = spp[i];
  float d0 = preds[i * 5 + 0] * st, d1 = preds[i * 5 + 1] * st;
  float d2 = preds[i * 5 + 2] * st, d3 = preds[i * 5 + 3] * st;
  float angp = preds[i * 5 + 4];
  float c = cosf(angp), s = sinf(angp);
  float w = d0 + d2, h = d1 + d3;
  float otx = (d2 - d0) * 0.5f, oty = (d3 - d1) * 0.5f;
  float dox = c * otx - s * oty, doy = s * otx + c * oty;
  const float PI = 3.14159265358979323846f;
  float a = fmodf(angp + PI * 0.5f, PI);
  if (a < 0.f) a += PI;
  a -= PI * 0.5f;

  float iou = obb_iou(ptx + dox, pty + doy, w, h, a, gx, gy, gw, gh, ga);
  cand_v[g * MAXC + j] = 0.2f * ctn + 0.2f * iou + 0.6f * prob;
}

// Wave-parallel top-15 per gt. 64 lanes hold <=4 candidates each; each round
// is a 6-step shfl_xor max of key = (val_bits<<32)|~i  (value desc, index asc
// = exact lax.top_k tie rule). All costs > 0, so rounds = min(15, cnt)
// implements the vals != 0 filter. Winners atomicMax the per-point area key:
// (area_bits<<32)|(G-1-g) -> max area, min g on ties (jnp.argmax rule).
__global__ void k_top(const int* __restrict__ cand_cnt,
                      const int* __restrict__ cand_i,
                      const float* __restrict__ cand_v,
                      const float* __restrict__ gtb,
                      unsigned long long* __restrict__ point_key,
                      int G) {
  int g = blockIdx.x;
  int lane = threadIdx.x;
  int cnt = cand_cnt[g];
  if (cnt > MAXC) cnt = MAXC;
  float v[4];
  int ii[4];
#pragma unroll
  for (int k = 0; k < 4; k++) {
    int j = lane + 64 * k;
    if (j < cnt) { v[k] = cand_v[g * MAXC + j]; ii[k] = cand_i[g * MAXC + j]; }
    else { v[k] = 0.f; ii[k] = 0; }
  }
  float area = gtb[g * 5 + 2] * gtb[g * 5 + 3];
  unsigned long long area_key =
      (((unsigned long long)__float_as_uint(area)) << 32) |
      (unsigned long long)(unsigned)(G - 1 - g);
  int rounds = cnt < TOPKK ? cnt : TOPKK;
  for (int r = 0; r < rounds; r++) {
    unsigned long long best = 0ull;
    int bk = -1;
#pragma unroll
    for (int k = 0; k < 4; k++) {
      if (v[k] > 0.f) {
        unsigned long long key =
            ((unsigned long long)__float_as_uint(v[k]) << 32) |
            (unsigned long long)(0xFFFFFFFFu - (unsigned)ii[k]);
        if (key > best) { best = key; bk = k; }
      }
    }
    unsigned long long b2 = best;
#pragma unroll
    for (int o = 32; o > 0; o >>= 1) {
      unsigned long long other = __shfl_xor(b2, o, 64);
      if (other > b2) b2 = other;
    }
    if (b2 == 0ull) break;
    if (best == b2 && bk >= 0) v[bk] = 0.f;  // unique owner consumes slot
    if (lane == 0) {
      unsigned iwin = 0xFFFFFFFFu - (unsigned)(b2 & 0xFFFFFFFFull);
      atomicMax(&point_key[iwin], area_key);
    }
  }
}

// Per point: resolve key -> (ind, label), count matches, write bt/at.
__global__ void k_assign(const unsigned long long* __restrict__ point_key,
                         const float* __restrict__ pts,
                         const float* __restrict__ spp,
                         const float* __restrict__ gtb,
                         const int* __restrict__ gtl,
                         int* __restrict__ counts,
                         float* __restrict__ out_labels,
                         float* __restrict__ out_bt,
                         float* __restrict__ out_at,
                         int N, int G) {
  int i = blockIdx.x * blockDim.x + threadIdx.x;
  if (i >= N) return;
  unsigned long long key = point_key[i];
  int g = 0;
  if (key != 0ull) {
    g = (G - 1) - (int)(key & 0xFFFFFFFFull);
    out_labels[i] = (float)gtl[g];
    atomicAdd(&counts[g], 1);
  } else {
    out_labels[i] = BG_F;  // argmax of all-zero row -> ind 0, label BG
  }
  float gx = gtb[g * 5 + 0], gy = gtb[g * 5 + 1];
  float gw = gtb[g * 5 + 2], gh = gtb[g * 5 + 3], ga = gtb[g * 5 + 4];
  float cg = cosf(ga), sg = sinf(ga);
  float px = pts[i * 2 + 0] - gx, py = pts[i * 2 + 1] - gy;
  float ox = px * cg + py * sg, oy = -px * sg + py * cg;
  float st = spp[i];
  out_bt[i * 4 + 0] = (gw * 0.5f + ox) / st;
  out_bt[i * 4 + 1] = (gh * 0.5f + oy) / st;
  out_bt[i * 4 + 2] = (gw * 0.5f - ox) / st;
  out_bt[i * 4 + 3] = (gh * 0.5f - oy) / st;
  out_at[i] = ga;
}

// Serial: unmatched gts claim their anchor point (ascending g, overwrite =
// last wins, matching XLA scatter), rewriting that point's outputs.
__global__ void k_fix(const int* __restrict__ counts,
                      const unsigned long long* __restrict__ cent_key,
                      const float* __restrict__ pts,
                      const float* __restrict__ spp,
                      const float* __restrict__ gtb,
                      const int* __restrict__ gtl,
                      float* __restrict__ out_labels,
                      float* __restrict__ out_bt,
                      float* __restrict__ out_at,
                      int G) {
  if (blockIdx.x != 0 || threadIdx.x != 0) return;
  for (int g = 0; g < G; g++) {
    if (counts[g] == 0) {
      unsigned i = 0xFFFFFFFFu - (unsigned)(cent_key[g] & 0xFFFFFFFFull);
      out_labels[i] = (float)gtl[g];
      float gx = gtb[g * 5 + 0], gy = gtb[g * 5 + 1];
      float gw = gtb[g * 5 + 2], gh = gtb[g * 5 + 3], ga = gtb[g * 5 + 4];
      float cg = cosf(ga), sg = sinf(ga);
      float px = pts[i * 2 + 0] - gx, py = pts[i * 2 + 1] - gy;
      float ox = px * cg + py * sg, oy = -px * sg + py * cg;
      float st = spp[i];
      out_bt[i * 4 + 0] = (gw * 0.5f + ox) / st;
      out_bt[i * 4 + 1] = (gh * 0.5f + oy) / st;
      out_bt[i * 4 + 2] = (gw * 0.5f - ox) / st;
      out_bt[i * 4 + 3] = (gh * 0.5f - oy) / st;
      out_at[i] = ga;
    }
  }
}

extern "C" void kernel_launch(void* const* d_in, const int* in_sizes, int n_in,
                              void* d_out, int out_size, void* d_ws, size_t ws_size,
                              hipStream_t stream) {
  const float* pts   = (const float*)d_in[0];
  const float* rr    = (const float*)d_in[1];
  const float* spp   = (const float*)d_in[2];
  const float* gtb   = (const float*)d_in[3];
  const int*   gtl   = (const int*)d_in[4];
  const float* preds = (const float*)d_in[5];
  const float* probs = (const float*)d_in[6];
  int N = in_sizes[0] / 2;
  int G = in_sizes[3] / 5;

  float* out = (float*)d_out;
  float* out_labels = out;                   // N
  float* out_bt     = out + N;               // N*4
  float* out_at     = out + 5 * (size_t)N;   // N

  // workspace layout (zeroed region first, 8-byte types first)
  unsigned long long* point_key = (unsigned long long*)d_ws;   // N
  unsigned long long* cent_key  = point_key + N;               // G
  int* cand_cnt = (int*)(cent_key + G);                        // G
  int* counts   = cand_cnt + G;                                // G
  int* cand_i   = counts + G;                                  // G*MAXC
  float* cand_v = (float*)(cand_i + (size_t)G * MAXC);         // G*MAXC

  size_t zbytes = (size_t)N * 8 + (size_t)G * 8 + (size_t)G * 4 * 2;
  hipMemsetAsync(d_ws, 0, zbytes, stream);

  const int thr = 256;
  int BPG = (N + thr - 1) / thr;
  hipLaunchKernelGGL(k_scanc, dim3(G * BPG), dim3(thr), 0, stream,
                     pts, rr, spp, gtb, cent_key, cand_cnt, cand_i, N, G, BPG);
  hipLaunchKernelGGL(k_iou, dim3(G), dim3(MAXC), 0, stream,
                     pts, spp, gtb, gtl, preds, probs,
                     cand_cnt, cand_i, cand_v, G);
  hipLaunchKernelGGL(k_top, dim3(G), dim3(64), 0, stream,
                     cand_cnt, cand_i, cand_v, gtb, point_key, G);
  hipLaunchKernelGGL(k_assign, dim3((N + thr - 1) / thr), dim3(thr), 0, stream,
                     point_key, pts, spp, gtb, gtl, counts,
                     out_labels, out_bt, out_at, N, G);
  hipLaunchKernelGGL(k_fix, dim3(1), dim3(64), 0, stream,
                     counts, cent_key, pts, spp, gtb, gtl,
                     out_labels, out_bt, out_at, G);
}